// Round 6
// baseline (118.730 us; speedup 1.0000x reference)
//
#include <hip/hip_runtime.h>
#include <math.h>

#define SLICES 32
#define ROWS_PER_SLICE 16
#define NBOXES 160

static __device__ __forceinline__ float fast_sigmoid(float x) {
    return __builtin_amdgcn_rcpf(1.0f + __expf(-x));
}

// K1: build the painted-pixel bitmask for all (batch, row) into global.
// grid (SLICES, 64) x 256 thr; thread t = (row_l = t>>4, word = t&15).
// Box phase = R5's verified readlane scan (zero LDS).
__global__ __launch_bounds__(256) void mask_kernel(
    const int* __restrict__ targets, unsigned* __restrict__ gmask)
{
    const int t = threadIdx.x;
    const int slice = blockIdx.x;
    const int b = blockIdx.y;
    const int r0 = slice * ROWS_PER_SLICE;
    const int lane = t & 63;

    const int4* tg = (const int4*)targets + (size_t)b * NBOXES;
    int4 gb0 = tg[lane];
    int4 gb1 = tg[64 + lane];
    int4 gb2 = (lane < 32) ? tg[128 + lane] : make_int4(0, 0, 0, 0);

    unsigned px0, py0, px1, py1, px2, py2;
    auto clip = [&](int4 g, unsigned& px, unsigned& py) -> bool {
        int x1 = min(g.x, 512), y1 = min(g.y, 512);
        int x2 = min(g.x + g.z, 512), y2 = min(g.y + g.w, 512);
        int cx1 = max(x1, r0), cx2 = min(x2, r0 + ROWS_PER_SLICE);
        px = (unsigned)cx1 | ((unsigned)cx2 << 16);
        py = (unsigned)y1 | ((unsigned)y2 << 16);
        return (cx2 > cx1) && (y2 > y1);
    };
    bool k0 = clip(gb0, px0, py0);
    bool k1 = clip(gb1, px1, py1);
    bool k2 = clip(gb2, px2, py2) && (lane < 32);
    unsigned long long m0 = __ballot(k0);
    unsigned long long m1 = __ballot(k1);
    unsigned long long m2 = __ballot(k2);

    const int r = r0 + (t >> 4);
    const unsigned wb = (unsigned)(t & 15) * 32u;
    unsigned m = 0;
    auto scan = [&](unsigned long long mk, unsigned px, unsigned py) {
        while (mk) {
            int k = (int)__builtin_ctzll(mk);
            mk &= mk - 1;
            unsigned rx = (unsigned)__builtin_amdgcn_readlane((int)px, k);
            unsigned ry = (unsigned)__builtin_amdgcn_readlane((int)py, k);
            int x1 = (int)(rx & 0xffffu), x2 = (int)(rx >> 16);
            unsigned y1 = ry & 0xffffu, y2 = ry >> 16;
            bool in_row = (r >= x1) && (r < x2);
            unsigned lo = y1 > wb ? y1 : wb;
            unsigned hi = y2 < wb + 32u ? y2 : wb + 32u;
            int nn = (int)hi - (int)lo;
            unsigned bits = 0xFFFFFFFFu >> ((32 - nn) & 31);
            unsigned contrib = bits << ((lo - wb) & 31u);
            m |= (in_row && nn > 0) ? contrib : 0u;
        }
    };
    scan(m0, px0, py0);
    scan(m1, px1, py1);
    scan(m2, px2, py2);
    // layout: gmask[b*8192 + row*16 + word]; coalesced (256 consec dwords).
    gmask[(size_t)b * 8192 + (size_t)r0 * 16 + t] = m;
}

// K2: pure streaming — zero LDS, zero barriers. 16 loads issued up front
// (8 mask dwords + 8 float4), then sigmoid + masked accumulate; per-WAVE
// partials written straight to global (no cross-wave reduction).
__global__ __launch_bounds__(256, 6) void stream_kernel(
    const float* __restrict__ pred, const unsigned* __restrict__ gmask,
    float* __restrict__ partials)
{
    const int t = threadIdx.x;
    const int slice = blockIdx.x;
    const int b = blockIdx.y;
    const int r0 = slice * ROWS_PER_SLICE;
    const int lane = t & 63, wave = t >> 6;
    const int col4 = t & 127;
    const int rb = t >> 7;  // 0 or 1; rows handled: rb + 2k, k=0..7
    const int widx = col4 >> 3;
    const unsigned bb = (unsigned)(col4 & 7) * 4u;

    const unsigned* gm = gmask + (size_t)b * 8192 + (size_t)(r0 + rb) * 16 + widx;
    unsigned w0 = gm[0 * 32];
    unsigned w1 = gm[1 * 32];
    unsigned w2 = gm[2 * 32];
    unsigned w3 = gm[3 * 32];
    unsigned w4 = gm[4 * 32];
    unsigned w5 = gm[5 * 32];
    unsigned w6 = gm[6 * 32];
    unsigned w7 = gm[7 * 32];

    const float4* p4 = (const float4*)pred;
    const size_t g0 = (size_t)b * 65536 + (size_t)(r0 + rb) * 128 + col4;
    float4 v0 = p4[g0 + 0 * 256];
    float4 v1 = p4[g0 + 1 * 256];
    float4 v2 = p4[g0 + 2 * 256];
    float4 v3 = p4[g0 + 3 * 256];
    float4 v4 = p4[g0 + 4 * 256];
    float4 v5 = p4[g0 + 5 * 256];
    float4 v6 = p4[g0 + 6 * 256];
    float4 v7 = p4[g0 + 7 * 256];

    float psum = 0.0f, isum = 0.0f;
    int cnt = 0;
#define ACC(V, W)                                                       \
    {                                                                   \
        const unsigned n = ((W) >> bb) & 0xFu;                          \
        float s0 = fast_sigmoid((V).x);                                 \
        float s1 = fast_sigmoid((V).y);                                 \
        float s2 = fast_sigmoid((V).z);                                 \
        float s3 = fast_sigmoid((V).w);                                 \
        psum += (s0 + s1) + (s2 + s3);                                  \
        cnt += __popc(n);                                               \
        isum += ((n & 1u) ? s0 : 0.0f) + ((n & 2u) ? s1 : 0.0f)         \
              + ((n & 4u) ? s2 : 0.0f) + ((n & 8u) ? s3 : 0.0f);        \
    }
    ACC(v0, w0) ACC(v1, w1) ACC(v2, w2) ACC(v3, w3)
    ACC(v4, w4) ACC(v5, w5) ACC(v6, w6) ACC(v7, w7)
#undef ACC
    float csum = (float)cnt;

    for (int off = 32; off > 0; off >>= 1) {
        psum += __shfl_down(psum, off);
        isum += __shfl_down(isum, off);
        csum += __shfl_down(csum, off);
    }
    if (lane == 0) {
        float* o = partials + (((size_t)b * SLICES + slice) * 4 + wave) * 3;
        o[0] = psum; o[1] = isum; o[2] = csum;
    }
}

// K3: one lane per batch folds 32 slices x 4 waves of partials.
__global__ __launch_bounds__(64) void final_kernel(
    const float* __restrict__ partials, float* __restrict__ out)
{
    const int b = threadIdx.x;  // 0..63
    double P = 0, I = 0, C = 0;
    const float* p = partials + (size_t)b * SLICES * 4 * 3;
    for (int s = 0; s < SLICES * 4; ++s) {
        P += (double)p[s * 3 + 0];
        I += (double)p[s * 3 + 1];
        C += (double)p[s * 3 + 2];
    }
    const double inter = 255.0 * I;
    const double tsum  = 255.0 * C;
    double loss = (inter + 1.0) / (P + tsum - inter + 1.0);
    for (int off = 32; off > 0; off >>= 1) loss += __shfl_down(loss, off);
    if (b == 0) out[0] = (float)(1.0 - loss / 64.0);
}

extern "C" void kernel_launch(void* const* d_in, const int* in_sizes, int n_in,
                              void* d_out, int out_size, void* d_ws, size_t ws_size,
                              hipStream_t stream) {
    const float* pred    = (const float*)d_in[0];  // (64,1,512,512) f32
    const int*   targets = (const int*)d_in[1];    // (64,5,32,4) i32
    float* out = (float*)d_out;                    // 1 f32 scalar

    // ws layout: [0, 96 KiB) per-wave partials; [96 KiB, +2 MiB) bitmask.
    float* partials = (float*)d_ws;                          // 64*32*4*3 f32
    unsigned* gmask = (unsigned*)((char*)d_ws + (96 << 10)); // 64*8192 u32

    dim3 grid(SLICES, 64);
    mask_kernel<<<grid, 256, 0, stream>>>(targets, gmask);
    stream_kernel<<<grid, 256, 0, stream>>>(pred, gmask, partials);
    final_kernel<<<1, 64, 0, stream>>>(partials, out);
}